// Round 8
// baseline (408.214 us; speedup 1.0000x reference)
//
#include <hip/hip_runtime.h>
#include <cmath>

// LoRAAttention, MI355X round 13.
//  - LoRA folded into effective weights (exact).
//  - QKV + proj GEMMs: 256x256 tile, BK=64, 8 waves, counted-vmcnt DOUBLE
//    BUFFER (minimal T3/T4 schedule). Rounds 11/12 failed at ~500 TF because
//    the schedule was order-pinned (3 sched_barriers or memory-clobber asm per
//    phase = m141 failure mode, 22 conservative waitcnts). This round: ONE
//    sched_barrier(0) per K-iter (pins ds_reads before the barrier that
//    precedes the same-region overwrite - the only real race), raw s_barrier,
//    clobber-free counted vmcnt(8), everything else free for the scheduler.
//  - Attention: round-10 2-q-tile kernel (LDS-reuse), unchanged.
//  - Preps fully parallelized.

#define DEVI __device__ __forceinline__

typedef float f32x4 __attribute__((ext_vector_type(4)));
typedef float f32x16 __attribute__((ext_vector_type(16)));
typedef short s16x8 __attribute__((ext_vector_type(8)));
typedef __bf16 b16x8 __attribute__((ext_vector_type(8)));
typedef unsigned int u32x4 __attribute__((ext_vector_type(4)));

static constexpr int MTOT = 16384;   // B*N
static constexpr int C = 768;
static constexpr int N3 = 2304;

DEVI unsigned short f2bf(float x) {
  unsigned int u = __builtin_bit_cast(unsigned int, x);
  return (unsigned short)((u + 0x7FFFu + ((u >> 16) & 1u)) >> 16);
}

DEVI f32x16 mfma32(s16x8 a, s16x8 b, f32x16 c) {
  return __builtin_amdgcn_mfma_f32_32x32x16_bf16(
      __builtin_bit_cast(b16x8, a), __builtin_bit_cast(b16x8, b), c, 0, 0, 0);
}

DEVI void async16(const void* g, void* l) {
  __builtin_amdgcn_global_load_lds(
      (__attribute__((address_space(1))) void*)g,
      (__attribute__((address_space(3))) void*)l, 16, 0, 0);
}

DEVI unsigned cvtpk_bf16(float lo, float hi2) {
  unsigned r;
  asm("v_cvt_pk_bf16_f32 %0, %1, %2" : "=v"(r) : "v"(lo), "v"(hi2));
  return r;
}

// ---------------- prep kernels ----------------

__global__ __launch_bounds__(256) void k_prep_x(const float* __restrict__ x,
                                                unsigned short* __restrict__ xb) {
  int idx = (blockIdx.x * 256 + threadIdx.x) * 4;
  float4 v = *(const float4*)(x + idx);
  uint2 p;
  p.x = (unsigned int)f2bf(v.x) | ((unsigned int)f2bf(v.y) << 16);
  p.y = (unsigned int)f2bf(v.z) | ((unsigned int)f2bf(v.w) << 16);
  *(uint2*)(xb + idx) = p;
}

__global__ __launch_bounds__(256) void k_prep_wqkv(
    const float* __restrict__ W, const float* __restrict__ Aq,
    const float* __restrict__ Bq, const float* __restrict__ Ak,
    const float* __restrict__ Bk, const float* __restrict__ Av,
    const float* __restrict__ Bv, unsigned short* __restrict__ out) {
  int idx = blockIdx.x * 256 + threadIdx.x;  // n*768 + c
  int n = idx / 768, c = idx - n * 768;
  int s = n / 768, co = n - s * 768;
  const float* A = (s == 0) ? Aq : (s == 1) ? Ak : Av;
  const float* Bm = (s == 0) ? Bq : (s == 1) ? Bk : Bv;
  float acc = W[idx];
#pragma unroll
  for (int r = 0; r < 16; ++r) acc += Bm[co * 16 + r] * A[r * 768 + c];
  out[idx] = f2bf(acc);
}

// M[r][j] = sum_c Ao[r][c] * Wp[c][j]; grid (16 r, 12 jb), 256 thr
__global__ __launch_bounds__(256) void k_prep_M(const float* __restrict__ Ao,
                                                const float* __restrict__ Wp,
                                                float* __restrict__ M) {
  __shared__ float red[4][64];
  const int r = blockIdx.x, j0 = blockIdx.y * 64;
  const int jl = threadIdx.x & 63, cs = threadIdx.x >> 6;
  float acc = 0.f;
#pragma unroll 4
  for (int c = cs * 192; c < cs * 192 + 192; ++c)
    acc += Ao[r * 768 + c] * Wp[c * 768 + j0 + jl];
  red[cs][jl] = acc;
  __syncthreads();
  if (cs == 0)
    M[r * 768 + j0 + jl] = red[0][jl] + red[1][jl] + red[2][jl] + red[3][jl];
}

__global__ __launch_bounds__(256) void k_prep_wpe(const float* __restrict__ Wp,
                                                  const float* __restrict__ Bo,
                                                  const float* __restrict__ M,
                                                  unsigned short* __restrict__ out) {
  int idx = blockIdx.x * 256 + threadIdx.x;  // n*768 + j
  int n = idx / 768, j = idx - n * 768;
  float acc = Wp[idx];
#pragma unroll
  for (int r = 0; r < 16; ++r) acc += Bo[n * 16 + r] * M[r * 768 + j];
  out[idx] = f2bf(acc);
}

// single block: bv[r] = Ao[r]·bp, then beff = bp + Bo·bv
__global__ __launch_bounds__(256) void k_prep_beff(const float* __restrict__ bp,
                                                   const float* __restrict__ Ao,
                                                   const float* __restrict__ Bo,
                                                   float* __restrict__ beff) {
  __shared__ float red[256];
  __shared__ float bv[16];
  const int t = threadIdx.x;
  const int r = t >> 4, cs = t & 15;
  float a = 0.f;
#pragma unroll 4
  for (int c = cs * 48; c < cs * 48 + 48; ++c) a += Ao[r * 768 + c] * bp[c];
  red[t] = a;
  __syncthreads();
  if (cs == 0) {
    float s = 0.f;
#pragma unroll
    for (int k = 0; k < 16; ++k) s += red[r * 16 + k];
    bv[r] = s;
  }
  __syncthreads();
#pragma unroll
  for (int it = 0; it < 3; ++it) {
    const int n = it * 256 + t;
    float acc = bp[n];
#pragma unroll
    for (int r2 = 0; r2 < 16; ++r2) acc += Bo[n * 16 + r2] * bv[r2];
    beff[n] = acc;
  }
}

// ---------------- 256x256 counted-vmcnt dbuf GEMM core (K=768, BK=64) -------
// A [M][768], Bw [N][768] bf16 row-major. 8 waves: wm=w>>2 (2), wn=w&3 (4).
// Per-wave out 128x64 = 4mi x 2nd tiles of 32x32. LDS 128KB = 2 bufs x
// (A 256x64 @0 + B 256x64 @16384 shorts). 16B chunk c of row rr stored at
// chunk c^(rr&7) (pre-swizzled global src, linear LDS dest); reads XOR same.
// Per kt: read 24 b128 from buf -> lgkmcnt(0) -> sched_barrier -> s_barrier ->
// issue stage(kt+2 -> buf) -> 32 MFMA -> vmcnt(8) [kt+1 landed, kt+2 in
// flight] -> s_barrier. Never drains vmcnt to 0 mid-loop.

template <bool SWAP>
DEVI void g256_core(const unsigned short* __restrict__ Ag,
                    const unsigned short* __restrict__ Bg,
                    short* lds, f32x16 (&acc)[4][2]) {
  const int t = threadIdx.x;
  const int w = t >> 6, l = t & 63;
  const int wm = w >> 2, wn = w & 3, lc = l & 31, hi = l >> 5;

  // hoisted swizzled read offsets (shorts, within a 32768-short buf)
  int aoff[4][4], boff[2][4];
#pragma unroll
  for (int mi = 0; mi < 4; ++mi)
#pragma unroll
    for (int kc = 0; kc < 4; ++kc) {
      const int rr = wm * 128 + mi * 32 + lc;
      aoff[mi][kc] = rr * 64 + (((kc * 2 + hi) ^ (rr & 7)) * 8);
    }
#pragma unroll
  for (int nd = 0; nd < 2; ++nd)
#pragma unroll
    for (int kc = 0; kc < 4; ++kc) {
      const int rr = wn * 64 + nd * 32 + lc;
      boff[nd][kc] = 16384 + rr * 64 + (((kc * 2 + hi) ^ (rr & 7)) * 8);
    }

  // stage one half-tile (128 rows x 64 cols): 2 async16/thread, swizzled src
  auto stageHT = [&](const unsigned short* G, int row0, int k0, int lbase) {
#pragma unroll
    for (int it = 0; it < 2; ++it) {
      const int s16 = it * 512 + t;
      const int rr = s16 >> 3;
      const int cg = (s16 & 7) ^ (rr & 7);
      async16(G + (size_t)(row0 + rr) * 768 + k0 + cg * 8, lds + lbase + s16 * 8);
    }
  };
  // stage a full K-tile (A 256x64 + B 256x64) into buf base: 8 loads/thread
  auto stageKT = [&](int kt, int base) {
    const int k0 = kt * 64;
    stageHT(Ag, 0, k0, base);
    stageHT(Ag, 128, k0, base + 8192);
    stageHT(Bg, 0, k0, base + 16384);
    stageHT(Bg, 128, k0, base + 24576);
  };

  stageKT(0, 0);
  stageKT(1, 32768);
  asm volatile("s_waitcnt vmcnt(8)");  // kt0 landed; kt1 in flight
  __builtin_amdgcn_s_barrier();

  for (int kt = 0; kt < 12; ++kt) {
    const int cb = (kt & 1) ? 32768 : 0;
    s16x8 af[4][4], bf[2][4];
#pragma unroll
    for (int mi = 0; mi < 4; ++mi)
#pragma unroll
      for (int kc = 0; kc < 4; ++kc)
        af[mi][kc] = *(const s16x8*)&lds[cb + aoff[mi][kc]];
#pragma unroll
    for (int nd = 0; nd < 2; ++nd)
#pragma unroll
      for (int kc = 0; kc < 4; ++kc)
        bf[nd][kc] = *(const s16x8*)&lds[cb + boff[nd][kc]];
    // my reads complete, and pinned before the barrier (stage below
    // overwrites this exact region; reads must not sink past it)
    asm volatile("s_waitcnt lgkmcnt(0)");
    __builtin_amdgcn_sched_barrier(0);
    __builtin_amdgcn_s_barrier();
    if (kt + 2 < 12) stageKT(kt + 2, cb);
    __builtin_amdgcn_s_setprio(1);
#pragma unroll
    for (int kc = 0; kc < 4; ++kc)
#pragma unroll
      for (int mi = 0; mi < 4; ++mi)
#pragma unroll
        for (int nd = 0; nd < 2; ++nd) {
          if constexpr (SWAP)
            acc[mi][nd] = mfma32(bf[nd][kc], af[mi][kc], acc[mi][nd]);
          else
            acc[mi][nd] = mfma32(af[mi][kc], bf[nd][kc], acc[mi][nd]);
        }
    __builtin_amdgcn_s_setprio(0);
    if (kt < 11) {
      if (kt + 2 < 12)
        asm volatile("s_waitcnt vmcnt(8)");  // kt+1 landed; kt+2 in flight
      else
        asm volatile("s_waitcnt vmcnt(0)");  // tail: kt+1 = last tile
      __builtin_amdgcn_s_barrier();
    }
  }
}

// ---------------- QKV GEMM: [16384,768] x [2304,768]^T -> q/k/vt bf16 -------
// grid (64 mblk, 9 nblk): nblk 0-2 q, 3-5 k (swapped: n in regs, packed d
// uint2 stores), 6-8 v (unswapped: pos in regs, transposed uint2 stores).

__global__ __launch_bounds__(512, 2) void k_gemm_qkv256(
    const unsigned short* __restrict__ A, const unsigned short* __restrict__ Bw,
    const float* __restrict__ bias, unsigned short* __restrict__ qb,
    unsigned short* __restrict__ kb, unsigned short* __restrict__ vtb) {
  __shared__ short lds[65536];  // 128 KiB
  const int t = threadIdx.x;
  const int w = t >> 6, l = t & 63;
  const int wm = w >> 2, wn = w & 3, lc = l & 31, hi = l >> 5;
  const int mblk = blockIdx.x, nblk = blockIdx.y;
  const unsigned short* Ag = A + (size_t)(mblk * 256) * 768;
  const unsigned short* Bg = Bw + (size_t)(nblk * 256) * 768;
  f32x16 acc[4][2] = {};
  const int seg = nblk / 3;  // 0=q 1=k 2=v
  const float c1 = 0.18033688011112042f;  // SCALE * log2(e)

  if (seg < 2) {
    g256_core<true>(Ag, Bg, lds, acc);
    unsigned short* dst = (seg == 0) ? qb : kb;
    const float scl = (seg == 0) ? c1 : 1.0f;
#pragma unroll
    for (int nd = 0; nd < 2; ++nd)
#pragma unroll
      for (int q2 = 0; q2 < 4; ++q2) {
        const int n0 = nblk * 256 + wn * 64 + nd * 32 + q2 * 8 + 4 * hi;
        const int nrel = n0 - seg * 768;
        const int hh = nrel >> 6, d0 = nrel & 63;
        const float4 bv4 = *(const float4*)(bias + n0);
#pragma unroll
        for (int mi = 0; mi < 4; ++mi) {
          const int m = mblk * 256 + wm * 128 + mi * 32 + lc;
          const int b = m >> 10, pos = m & 1023;
          uint2 pk;
          pk.x = (unsigned int)f2bf((acc[mi][nd][4 * q2 + 0] + bv4.x) * scl) |
                 ((unsigned int)f2bf((acc[mi][nd][4 * q2 + 1] + bv4.y) * scl) << 16);
          pk.y = (unsigned int)f2bf((acc[mi][nd][4 * q2 + 2] + bv4.z) * scl) |
                 ((unsigned int)f2bf((acc[mi][nd][4 * q2 + 3] + bv4.w) * scl) << 16);
          *(uint2*)&dst[(size_t)((b * 12 + hh) * 1024 + pos) * 64 + d0] = pk;
        }
      }
  } else {
    g256_core<false>(Ag, Bg, lds, acc);
#pragma unroll
    for (int nd = 0; nd < 2; ++nd) {
      const int n = nblk * 256 + wn * 64 + nd * 32 + lc;
      const int nrel = n - 1536;
      const int hh = nrel >> 6, d = nrel & 63;
      const float bvv = bias[n];
#pragma unroll
      for (int mi = 0; mi < 4; ++mi)
#pragma unroll
        for (int q2 = 0; q2 < 4; ++q2) {
          const int m0 = mblk * 256 + wm * 128 + mi * 32 + q2 * 8 + 4 * hi;
          const int b = m0 >> 10, pos0 = m0 & 1023;
          uint2 pk;
          pk.x = (unsigned int)f2bf(acc[mi][nd][4 * q2 + 0] + bvv) |
                 ((unsigned int)f2bf(acc[mi][nd][4 * q2 + 1] + bvv) << 16);
          pk.y = (unsigned int)f2bf(acc[mi][nd][4 * q2 + 2] + bvv) |
                 ((unsigned int)f2bf(acc[mi][nd][4 * q2 + 3] + bvv) << 16);
          *(uint2*)&vtb[(size_t)((b * 12 + hh) * 64 + d) * 1024 + pos0] = pk;
        }
    }
  }
}

// ---------------- proj GEMM: [16384,768] x [768,768]^T + b_eff -> f32 -------
// grid (64 mblk, 3 nblk), swapped: n in regs -> packed float4 stores.

__global__ __launch_bounds__(512, 2) void k_gemm_proj256(
    const unsigned short* __restrict__ A, const unsigned short* __restrict__ Bw,
    const float* __restrict__ bias, float* __restrict__ out) {
  __shared__ short lds[65536];  // 128 KiB
  const int t = threadIdx.x;
  const int w = t >> 6, l = t & 63;
  const int wm = w >> 2, wn = w & 3, lc = l & 31, hi = l >> 5;
  const int mblk = blockIdx.x, nblk = blockIdx.y;
  const unsigned short* Ag = A + (size_t)(mblk * 256) * 768;
  const unsigned short* Bg = Bw + (size_t)(nblk * 256) * 768;
  f32x16 acc[4][2] = {};
  g256_core<true>(Ag, Bg, lds, acc);
#pragma unroll
  for (int nd = 0; nd < 2; ++nd)
#pragma unroll
    for (int q2 = 0; q2 < 4; ++q2) {
      const int n0 = nblk * 256 + wn * 64 + nd * 32 + q2 * 8 + 4 * hi;
      const float4 bv4 = *(const float4*)(bias + n0);
#pragma unroll
      for (int mi = 0; mi < 4; ++mi) {
        const int m = mblk * 256 + wm * 128 + mi * 32 + lc;
        float4 o;
        o.x = acc[mi][nd][4 * q2 + 0] + bv4.x;
        o.y = acc[mi][nd][4 * q2 + 1] + bv4.y;
        o.z = acc[mi][nd][4 * q2 + 2] + bv4.z;
        o.w = acc[mi][nd][4 * q2 + 3] + bv4.w;
        *(float4*)&out[(size_t)m * 768 + n0] = o;
      }
    }
}

// ---------------- flash attention (32x32x16 MFMA, 2 q-tiles/block) ----------
// grid: (192 bh, 4 q-pairs of 256 rows), 256 threads (4 waves x 32 q-rows x2).
// Each K/V LDS fragment feeds TWO MFMAs (q-groups A and B).

__global__ __launch_bounds__(256, 2) void k_attn(
    const unsigned short* __restrict__ qg, const unsigned short* __restrict__ kg,
    const unsigned short* __restrict__ vtg, unsigned short* __restrict__ og) {
  __shared__ short k_lds[2][64 * 64];
  __shared__ short vt_lds[2][64 * 64];

  const int t = threadIdx.x;
  const int w = t >> 6, l = t & 63;
  const int lc = l & 31;        // col (qrow / d) within 32
  const int hi = l >> 5;        // lane half
  const int bh = blockIdx.x;    // 0..191
  const int qpair = blockIdx.y; // 0..3 (256 q-rows each)
  const int h = bh % 12, b = bh / 12;

  const unsigned short* Qg = qg + (size_t)(bh * 1024 + qpair * 256) * 64;
  const unsigned short* Kg = kg + (size_t)bh * 1024 * 64;
  const unsigned short* Vtg = vtg + (size_t)bh * 64 * 1024;

  const int srl = l >> 3;            // row-local 0..7
  const int sgc = (l & 7) ^ srl;     // swizzled global chunk 0..7

  // Q B-frags for both groups: col=qrow=lc, k-elems = d = kc*16 + hi*8 + j
  s16x8 qfA[4], qfB[4];
#pragma unroll
  for (int kc = 0; kc < 4; ++kc) {
    qfA[kc] = *(const s16x8*)(Qg + (w * 32 + lc) * 64 + kc * 16 + hi * 8);
    qfB[kc] = *(const s16x8*)(Qg + (128 + w * 32 + lc) * 64 + kc * 16 + hi * 8);
  }

  // Hoisted loop-invariant swizzled LDS offsets (shorts). Only `buf` varies.
  int koffs[2][4];   // [pg][kc]
#pragma unroll
  for (int pg = 0; pg < 2; ++pg)
#pragma unroll
    for (int kc = 0; kc < 4; ++kc)
      koffs[pg][kc] = (pg * 32 + lc) * 64 + (((kc * 2 + hi) ^ (lc & 7)) * 8);
  int voffs[2][4][2];  // [nd][mi][h2]
#pragma unroll
  for (int nd = 0; nd < 2; ++nd)
#pragma unroll
    for (int mi = 0; mi < 4; ++mi)
#pragma unroll
      for (int h2 = 0; h2 < 2; ++h2)
        voffs[nd][mi][h2] =
            (nd * 32 + lc) * 64 + (((2 * mi + h2) ^ (lc & 7)) * 8) + 4 * hi;

  auto stage = [&](int bufn, int tkv) {
#pragma unroll
    for (int it = 0; it < 2; ++it) {
      const int rbase = it * 32 + w * 8;
      async16(Kg + (size_t)(tkv * 64 + rbase + srl) * 64 + sgc * 8,
              &k_lds[bufn][rbase * 64]);
      async16(Vtg + (size_t)(rbase + srl) * 1024 + tkv * 64 + sgc * 8,
              &vt_lds[bufn][rbase * 64]);
    }
  };

  stage(0, 0);

  f32x16 oaccA[2] = {}, oaccB[2] = {};  // [nd] : D[qrow][d], col=d=nd*32+lc
  float llA = 0.f, llB = 0.f;

  for (int tkv = 0; tkv < 16; ++tkv) {
    const int buf = tkv & 1;
    __syncthreads();
    if (tkv < 15) stage(buf ^ 1, tkv + 1);

#pragma unroll
    for (int pg = 0; pg < 2; ++pg) {
      // GEMM1: S^T tile, rows pos = pg*32 + lc, cols qrow. ka reused for A,B.
      s16x8 ka[4];
#pragma unroll
      for (int kc = 0; kc < 4; ++kc)
        ka[kc] = *(const s16x8*)&k_lds[buf][koffs[pg][kc]];
      f32x16 stA = {}, stB = {};
#pragma unroll
      for (int kc = 0; kc < 4; ++kc) {
        stA = mfma32(ka[kc], qfA[kc], stA);
        stB = mfma32(ka[kc], qfB[kc], stB);
      }
      // exp2 + RNE bf16 pack + f32 l-sum, both groups.
      unsigned pkA[4][2], pkB[4][2];
#pragma unroll
      for (int q = 0; q < 4; ++q) {
        const float a0 = __builtin_amdgcn_exp2f(stA[4 * q + 0]);
        const float a1 = __builtin_amdgcn_exp2f(stA[4 * q + 1]);
        const float a2 = __builtin_amdgcn_exp2f(stA[4 * q + 2]);
        const float a3 = __builtin_amdgcn_exp2f(stA[4 * q + 3]);
        pkA[q][0] = cvtpk_bf16(a0, a1);
        pkA[q][1] = cvtpk_bf16(a2, a3);
        llA += (a0 + a1) + (a2 + a3);
        const float b0 = __builtin_amdgcn_exp2f(stB[4 * q + 0]);
        const float b1 = __builtin_amdgcn_exp2f(stB[4 * q + 1]);
        const float b2 = __builtin_amdgcn_exp2f(stB[4 * q + 2]);
        const float b3 = __builtin_amdgcn_exp2f(stB[4 * q + 3]);
        pkB[q][0] = cvtpk_bf16(b0, b1);
        pkB[q][1] = cvtpk_bf16(b2, b3);
        llB += (b0 + b1) + (b2 + b3);
      }
      // GEMM2: V fragment read once, used by both groups.
      __builtin_amdgcn_s_setprio(1);
#pragma unroll
      for (int m = 0; m < 2; ++m) {
        const int mi = pg * 2 + m;
        u32x4 faA, faB;
        faA[0] = pkA[2 * m][0];
        faA[1] = pkA[2 * m][1];
        faA[2] = pkA[2 * m + 1][0];
        faA[3] = pkA[2 * m + 1][1];
        faB[0] = pkB[2 * m][0];
        faB[1] = pkB[2 * m][1];
        faB[2] = pkB[2 * m + 1][0];
        faB[3] = pkB[2 * m + 1][1];
        const s16x8 pafA = __builtin_bit_cast(s16x8, faA);
        const s16x8 pafB = __builtin_bit_cast(s16x8, faB);
#pragma unroll
        for (int nd = 0; nd < 2; ++nd) {
          const uint2 vlo = *(const uint2*)&vt_lds[buf][voffs[nd][mi][0]];
          const uint2 vhi = *(const uint2*)&vt_lds[buf][voffs[nd][mi][1]];
          u32x4 vbu;
          vbu[0] = vlo.x;
          vbu[1] = vlo.y;
          vbu[2] = vhi.x;
          vbu[3] = vhi.y;
          const s16x8 vb = __builtin_bit_cast(s16x8, vbu);
          oaccA[nd] = mfma32(pafA, vb, oaccA[nd]);
          oaccB[nd] = mfma32(pafB, vb, oaccB[nd]);
        }
      }
      __builtin_amdgcn_s_setprio(0);
    }
  }

  // l per qrow (each group): lane (lc,hi) holds partial over half the pos
  // set; partner (lc,hi^1) the rest. Gather per output row via shfl.
  const float lqA = llA + __shfl_xor(llA, 32, 64);
  const float lqB = llB + __shfl_xor(llB, 32, 64);
  float linvA[16], linvB[16];
#pragma unroll
  for (int r = 0; r < 16; ++r) {
    const int qr = (r & 3) + 8 * (r >> 2) + 4 * hi;
    linvA[r] = 1.0f / __shfl(lqA, qr, 64);
    linvB[r] = 1.0f / __shfl(lqB, qr, 64);
  }

  const int orow0 = qpair * 256 + w * 32;
#pragma unroll
  for (int nd = 0; nd < 2; ++nd)
#pragma unroll
    for (int r = 0; r < 16; ++r) {
      const int qr = (r & 3) + 8 * (r >> 2) + 4 * hi;
      const int d = nd * 32 + lc;
      og[(size_t)(b * 1024 + orow0 + qr) * 768 + h * 64 + d] =
          f2bf(oaccA[nd][r] * linvA[r]);
      og[(size_t)(b * 1024 + orow0 + 128 + qr) * 768 + h * 64 + d] =
          f2bf(oaccB[nd][r] * linvB[r]);
    }
}

// ---------------- host ----------------

extern "C" void kernel_launch(void* const* d_in, const int* in_sizes, int n_in,
                              void* d_out, int out_size, void* d_ws, size_t ws_size,
                              hipStream_t stream) {
  const float* x = (const float*)d_in[0];
  const float* Wqkv = (const float*)d_in[1];
  const float* bqkv = (const float*)d_in[2];
  const float* Wp = (const float*)d_in[3];
  const float* bp = (const float*)d_in[4];
  const float* Aq = (const float*)d_in[5];
  const float* Bq = (const float*)d_in[6];
  const float* Ak = (const float*)d_in[7];
  const float* Bk = (const float*)d_in[8];
  const float* Av = (const float*)d_in[9];
  const float* Bv = (const float*)d_in[10];
  const float* Ao = (const float*)d_in[11];
  const float* Bo = (const float*)d_in[12];
  float* out = (float*)d_out;

  unsigned short* xb = (unsigned short*)d_ws;         // 16384*768
  unsigned short* wqkvb = xb + (size_t)MTOT * C;      // 2304*768
  unsigned short* wpeb = wqkvb + (size_t)N3 * C;      // 768*768
  unsigned short* qb = wpeb + (size_t)C * C;          // 192*1024*64
  unsigned short* kb = qb + (size_t)MTOT * C;
  unsigned short* vtb = kb + (size_t)MTOT * C;        // 192*64*1024 (transposed)
  float* Mbuf = (float*)(vtb + (size_t)MTOT * C);     // 16*768
  float* beff = Mbuf + 16 * 768;                      // 768
  unsigned short* ob = xb;  // alias: xb dead after QKV gemm

  k_prep_x<<<12288, 256, 0, stream>>>(x, xb);
  k_prep_wqkv<<<6912, 256, 0, stream>>>(Wqkv, Aq, Bq, Ak, Bk, Av, Bv, wqkvb);
  k_prep_M<<<dim3(16, 12), 256, 0, stream>>>(Ao, Wp, Mbuf);
  k_prep_wpe<<<2304, 256, 0, stream>>>(Wp, Bo, Mbuf, wpeb);
  k_prep_beff<<<1, 256, 0, stream>>>(bp, Ao, Bo, beff);

  k_gemm_qkv256<<<dim3(64, 9), 512, 0, stream>>>(xb, wqkvb, bqkv, qb, kb, vtb);
  k_attn<<<dim3(192, 4), 256, 0, stream>>>(qb, kb, vtb, ob);
  k_gemm_proj256<<<dim3(64, 3), 512, 0, stream>>>(ob, wpeb, beff, out);
}

// Round 9
// 341.747 us; speedup vs baseline: 1.1945x; 1.1945x over previous
//
#include <hip/hip_runtime.h>
#include <cmath>

// LoRAAttention, MI355X round 14.
//  - REVERT: QKV + proj GEMMs back to round-10 2-phase 128x128 kernels
//    (counted-vmcnt 256x256 refuted for this shape: 3 schedules all <=500 TF;
//    128KiB LDS -> 1 block/CU -> no cross-block latency hiding).
//  - NEW: prep kernels fused 5 -> 2 launches (x | wqkv | M | beff in one
//    multi-range kernel; wpe separate, consumes M). Total launches 8 -> 5:
//    ~143 us of the 350 us total is dispatch/reset overhead.
//  - Attention: round-10 2-q-tile kernel (LDS-reuse), unchanged.

#define DEVI __device__ __forceinline__

typedef float f32x4 __attribute__((ext_vector_type(4)));
typedef float f32x16 __attribute__((ext_vector_type(16)));
typedef short s16x8 __attribute__((ext_vector_type(8)));
typedef __bf16 b16x8 __attribute__((ext_vector_type(8)));
typedef unsigned int u32x4 __attribute__((ext_vector_type(4)));

static constexpr int MTOT = 16384;   // B*N
static constexpr int C = 768;
static constexpr int N3 = 2304;

DEVI unsigned short f2bf(float x) {
  unsigned int u = __builtin_bit_cast(unsigned int, x);
  return (unsigned short)((u + 0x7FFFu + ((u >> 16) & 1u)) >> 16);
}

DEVI f32x4 mfma16(s16x8 a, s16x8 b, f32x4 c) {
  return __builtin_amdgcn_mfma_f32_16x16x32_bf16(
      __builtin_bit_cast(b16x8, a), __builtin_bit_cast(b16x8, b), c, 0, 0, 0);
}

DEVI f32x16 mfma32(s16x8 a, s16x8 b, f32x16 c) {
  return __builtin_amdgcn_mfma_f32_32x32x16_bf16(
      __builtin_bit_cast(b16x8, a), __builtin_bit_cast(b16x8, b), c, 0, 0, 0);
}

DEVI void async16(const void* g, void* l) {
  __builtin_amdgcn_global_load_lds(
      (__attribute__((address_space(1))) void*)g,
      (__attribute__((address_space(3))) void*)l, 16, 0, 0);
}

DEVI unsigned cvtpk_bf16(float lo, float hi2) {
  unsigned r;
  asm("v_cvt_pk_bf16_f32 %0, %1, %2" : "=v"(r) : "v"(lo), "v"(hi2));
  return r;
}

// ---------------- fused prep kernel ----------------
// grid 19393 x 256:
//   [0, 12288)        prep_x    : f32 x -> bf16 xb (float4/thread)
//   [12288, 19200)    prep_wqkv : W_qkv + LoRA fold -> bf16 wqkvb
//   [19200, 19392)    prep_M    : M[r][j] = sum_c Ao[r][c] Wp[c][j]
//   19392             prep_beff : beff = bp + Bo (Ao bp)

__global__ __launch_bounds__(256) void k_prep_all(
    const float* __restrict__ x, unsigned short* __restrict__ xb,
    const float* __restrict__ W, const float* __restrict__ Aq,
    const float* __restrict__ Bq, const float* __restrict__ Ak,
    const float* __restrict__ Bk, const float* __restrict__ Av,
    const float* __restrict__ Bv, unsigned short* __restrict__ wqkvb,
    const float* __restrict__ Ao, const float* __restrict__ Wp,
    float* __restrict__ M, const float* __restrict__ bp,
    const float* __restrict__ Bo, float* __restrict__ beff) {
  __shared__ float smem[272];
  const int bid = blockIdx.x;
  const int t = threadIdx.x;

  if (bid < 12288) {
    // ---- prep_x
    int idx = (bid * 256 + t) * 4;
    float4 v = *(const float4*)(x + idx);
    uint2 p;
    p.x = (unsigned int)f2bf(v.x) | ((unsigned int)f2bf(v.y) << 16);
    p.y = (unsigned int)f2bf(v.z) | ((unsigned int)f2bf(v.w) << 16);
    *(uint2*)(xb + idx) = p;
  } else if (bid < 19200) {
    // ---- prep_wqkv
    int idx = (bid - 12288) * 256 + t;  // n*768 + c
    int n = idx / 768, c = idx - n * 768;
    int s = n / 768, co = n - s * 768;
    const float* A = (s == 0) ? Aq : (s == 1) ? Ak : Av;
    const float* Bm = (s == 0) ? Bq : (s == 1) ? Bk : Bv;
    float acc = W[idx];
#pragma unroll
    for (int r = 0; r < 16; ++r) acc += Bm[co * 16 + r] * A[r * 768 + c];
    wqkvb[idx] = f2bf(acc);
  } else if (bid < 19392) {
    // ---- prep_M (mb: r = mb&15, jb = mb>>4)
    const int mb = bid - 19200;
    const int r = mb & 15, j0 = (mb >> 4) * 64;
    const int jl = t & 63, cs = t >> 6;
    float acc = 0.f;
#pragma unroll 4
    for (int c = cs * 192; c < cs * 192 + 192; ++c)
      acc += Ao[r * 768 + c] * Wp[c * 768 + j0 + jl];
    smem[cs * 64 + jl] = acc;
    __syncthreads();
    if (cs == 0)
      M[r * 768 + j0 + jl] =
          smem[jl] + smem[64 + jl] + smem[128 + jl] + smem[192 + jl];
  } else {
    // ---- prep_beff
    float* red = smem;
    float* bv = smem + 256;
    const int r = t >> 4, cs = t & 15;
    float a = 0.f;
#pragma unroll 4
    for (int c = cs * 48; c < cs * 48 + 48; ++c) a += Ao[r * 768 + c] * bp[c];
    red[t] = a;
    __syncthreads();
    if (cs == 0) {
      float s = 0.f;
#pragma unroll
      for (int k = 0; k < 16; ++k) s += red[r * 16 + k];
      bv[r] = s;
    }
    __syncthreads();
#pragma unroll
    for (int it = 0; it < 3; ++it) {
      const int n = it * 256 + t;
      float acc = bp[n];
#pragma unroll
      for (int r2 = 0; r2 < 16; ++r2) acc += Bo[n * 16 + r2] * bv[r2];
      beff[n] = acc;
    }
  }
}

__global__ __launch_bounds__(256) void k_prep_wpe(const float* __restrict__ Wp,
                                                  const float* __restrict__ Bo,
                                                  const float* __restrict__ M,
                                                  unsigned short* __restrict__ out) {
  int idx = blockIdx.x * 256 + threadIdx.x;  // n*768 + j
  int n = idx / 768, j = idx - n * 768;
  float acc = Wp[idx];
#pragma unroll
  for (int r = 0; r < 16; ++r) acc += Bo[n * 16 + r] * M[r * 768 + j];
  out[idx] = f2bf(acc);
}

// ---------------- QKV GEMM: [16384,768] x [2304,768]^T -> q/k/vt bf16 --------
// One launch, grid (128,18): nblk<12 -> q/k (SWAP, packed d-stores), else v
// (transposed [bh][d][pos] stores). One barrier per K-iter (dbuf).

template <bool SWAP>
DEVI void qkv_body(const unsigned short* __restrict__ A,
                   const unsigned short* __restrict__ Bw,
                   const float* __restrict__ bias, int nblk,
                   unsigned short* __restrict__ qb,
                   unsigned short* __restrict__ kb,
                   unsigned short* __restrict__ vtb,
                   short (*la)[128 * 32], short (*lb)[128 * 32]) {
  const int t = threadIdx.x;
  const int w = t >> 6, l = t & 63;
  const int i = l & 15, qd = l >> 4;
  const int wm = w >> 1, wn = w & 1;
  const int mblk = blockIdx.x;

  const unsigned short* Ab = A + (size_t)(mblk * 128) * 768;
  const unsigned short* Bb = Bw + (size_t)(nblk * 128) * 768;
  const int sr = l >> 2;        // 0..15
  const int sc = (l & 3) * 8;   // 0,8,16,24

  auto stage = [&](int bufn, int kb_) {
    const int k0 = kb_ * 32;
#pragma unroll
    for (int j = 0; j < 2; ++j) {
      const int row = w * 32 + j * 16 + sr;
      async16(Ab + row * 768 + k0 + sc, &la[bufn][(w * 32 + j * 16) * 32]);
      async16(Bb + row * 768 + k0 + sc, &lb[bufn][(w * 32 + j * 16) * 32]);
    }
  };

  stage(0, 0);

  f32x4 acc[4][4] = {};

  for (int kb_ = 0; kb_ < 24; ++kb_) {
    const int buf = kb_ & 1;
    __syncthreads();
    if (kb_ < 23) stage(buf ^ 1, kb_ + 1);
    s16x8 af[4], bf[4];
#pragma unroll
    for (int mi = 0; mi < 4; ++mi)
      af[mi] = *(const s16x8*)&la[buf][(wm * 64 + mi * 16 + i) * 32 + qd * 8];
#pragma unroll
    for (int ni = 0; ni < 4; ++ni)
      bf[ni] = *(const s16x8*)&lb[buf][(wn * 64 + ni * 16 + i) * 32 + qd * 8];
#pragma unroll
    for (int mi = 0; mi < 4; ++mi)
#pragma unroll
      for (int ni = 0; ni < 4; ++ni) {
        if constexpr (SWAP)
          acc[mi][ni] = mfma16(bf[ni], af[mi], acc[mi][ni]);
        else
          acc[mi][ni] = mfma16(af[mi], bf[ni], acc[mi][ni]);
      }
  }

  const float c1 = 0.18033688011112042f;  // SCALE * log2(e)
  if constexpr (SWAP) {
    // q/k: lane i -> x-row (pos), reg r -> weight col (d): pack 4 d into 8B
#pragma unroll
    for (int ni = 0; ni < 4; ++ni) {
      const int n0 = nblk * 128 + wn * 64 + ni * 16 + qd * 4;
      const int s = n0 / 768;
      const int nrel = n0 - s * 768;
      const int h = nrel >> 6, d0 = nrel & 63;
      const float4 bv4 = *(const float4*)(bias + n0);
      unsigned short* dst = (s == 0) ? qb : kb;
      const float scl = (s == 0) ? c1 : 1.0f;
#pragma unroll
      for (int mi = 0; mi < 4; ++mi) {
        const int m = mblk * 128 + wm * 64 + mi * 16 + i;
        const int b = m >> 10, pos = m & 1023;
        uint2 pk;
        pk.x = (unsigned int)f2bf((acc[mi][ni][0] + bv4.x) * scl) |
               ((unsigned int)f2bf((acc[mi][ni][1] + bv4.y) * scl) << 16);
        pk.y = (unsigned int)f2bf((acc[mi][ni][2] + bv4.z) * scl) |
               ((unsigned int)f2bf((acc[mi][ni][3] + bv4.w) * scl) << 16);
        *(uint2*)&dst[(size_t)((b * 12 + h) * 1024 + pos) * 64 + d0] = pk;
      }
    }
  } else {
    // v: lane i -> weight col (d), reg r -> x-row (pos): transposed pack
#pragma unroll
    for (int ni = 0; ni < 4; ++ni) {
      const int n = nblk * 128 + wn * 64 + ni * 16 + i;
      const int nrel = n - 1536;
      const int h = nrel >> 6, d = nrel & 63;
      const float bvv = bias[n];
#pragma unroll
      for (int mi = 0; mi < 4; ++mi) {
        const int m0 = mblk * 128 + wm * 64 + mi * 16 + qd * 4;
        const int b = m0 >> 10, pos0 = m0 & 1023;
        uint2 pk;
        pk.x = (unsigned int)f2bf(acc[mi][ni][0] + bvv) |
               ((unsigned int)f2bf(acc[mi][ni][1] + bvv) << 16);
        pk.y = (unsigned int)f2bf(acc[mi][ni][2] + bvv) |
               ((unsigned int)f2bf(acc[mi][ni][3] + bvv) << 16);
        *(uint2*)&vtb[(size_t)((b * 12 + h) * 64 + d) * 1024 + pos0] = pk;
      }
    }
  }
}

__global__ __launch_bounds__(256) void k_gemm_qkv(
    const unsigned short* __restrict__ A, const unsigned short* __restrict__ Bw,
    const float* __restrict__ bias, unsigned short* __restrict__ qb,
    unsigned short* __restrict__ kb, unsigned short* __restrict__ vtb) {
  __shared__ short la[2][128 * 32];
  __shared__ short lb[2][128 * 32];
  if (blockIdx.y < 12)
    qkv_body<true>(A, Bw, bias, blockIdx.y, qb, kb, vtb, la, lb);
  else
    qkv_body<false>(A, Bw, bias, blockIdx.y, qb, kb, vtb, la, lb);
}

// ---------------- flash attention (32x32x16 MFMA, 2 q-tiles/block) ----------
// grid: (192 bh, 4 q-pairs of 256 rows), 256 threads (4 waves x 32 q-rows x2).
// Each K/V LDS fragment feeds TWO MFMAs (q-groups A and B).

__global__ __launch_bounds__(256, 2) void k_attn(
    const unsigned short* __restrict__ qg, const unsigned short* __restrict__ kg,
    const unsigned short* __restrict__ vtg, unsigned short* __restrict__ og) {
  __shared__ short k_lds[2][64 * 64];
  __shared__ short vt_lds[2][64 * 64];

  const int t = threadIdx.x;
  const int w = t >> 6, l = t & 63;
  const int lc = l & 31;        // col (qrow / d) within 32
  const int hi = l >> 5;        // lane half
  const int bh = blockIdx.x;    // 0..191
  const int qpair = blockIdx.y; // 0..3 (256 q-rows each)
  const int h = bh % 12, b = bh / 12;

  const unsigned short* Qg = qg + (size_t)(bh * 1024 + qpair * 256) * 64;
  const unsigned short* Kg = kg + (size_t)bh * 1024 * 64;
  const unsigned short* Vtg = vtg + (size_t)bh * 64 * 1024;

  const int srl = l >> 3;            // row-local 0..7
  const int sgc = (l & 7) ^ srl;     // swizzled global chunk 0..7

  // Q B-frags for both groups: col=qrow=lc, k-elems = d = kc*16 + hi*8 + j
  s16x8 qfA[4], qfB[4];
#pragma unroll
  for (int kc = 0; kc < 4; ++kc) {
    qfA[kc] = *(const s16x8*)(Qg + (w * 32 + lc) * 64 + kc * 16 + hi * 8);
    qfB[kc] = *(const s16x8*)(Qg + (128 + w * 32 + lc) * 64 + kc * 16 + hi * 8);
  }

  // Hoisted loop-invariant swizzled LDS offsets (shorts). Only `buf` varies.
  int koffs[2][4];   // [pg][kc]
#pragma unroll
  for (int pg = 0; pg < 2; ++pg)
#pragma unroll
    for (int kc = 0; kc < 4; ++kc)
      koffs[pg][kc] = (pg * 32 + lc) * 64 + (((kc * 2 + hi) ^ (lc & 7)) * 8);
  int voffs[2][4][2];  // [nd][mi][h2]
#pragma unroll
  for (int nd = 0; nd < 2; ++nd)
#pragma unroll
    for (int mi = 0; mi < 4; ++mi)
#pragma unroll
      for (int h2 = 0; h2 < 2; ++h2)
        voffs[nd][mi][h2] =
            (nd * 32 + lc) * 64 + (((2 * mi + h2) ^ (lc & 7)) * 8) + 4 * hi;

  auto stage = [&](int bufn, int tkv) {
#pragma unroll
    for (int it = 0; it < 2; ++it) {
      const int rbase = it * 32 + w * 8;
      async16(Kg + (size_t)(tkv * 64 + rbase + srl) * 64 + sgc * 8,
              &k_lds[bufn][rbase * 64]);
      async16(Vtg + (size_t)(rbase + srl) * 1024 + tkv * 64 + sgc * 8,
              &vt_lds[bufn][rbase * 64]);
    }
  };

  stage(0, 0);

  f32x16 oaccA[2] = {}, oaccB[2] = {};  // [nd] : D[qrow][d], col=d=nd*32+lc
  float llA = 0.f, llB = 0.f;

  for (int tkv = 0; tkv < 16; ++tkv) {
    const int buf = tkv & 1;
    __syncthreads();
    if (tkv < 15) stage(buf ^ 1, tkv + 1);

#pragma unroll
    for (int pg = 0; pg < 2; ++pg) {
      // GEMM1: S^T tile, rows pos = pg*32 + lc, cols qrow. ka reused for A,B.
      s16x8 ka[4];
#pragma unroll
      for (int kc = 0; kc < 4; ++kc)
        ka[kc] = *(const s16x8*)&k_lds[buf][koffs[pg][kc]];
      f32x16 stA = {}, stB = {};
#pragma unroll
      for (int kc = 0; kc < 4; ++kc) {
        stA = mfma32(ka[kc], qfA[kc], stA);
        stB = mfma32(ka[kc], qfB[kc], stB);
      }
      // exp2 + RNE bf16 pack + f32 l-sum, both groups.
      unsigned pkA[4][2], pkB[4][2];
#pragma unroll
      for (int q = 0; q < 4; ++q) {
        const float a0 = __builtin_amdgcn_exp2f(stA[4 * q + 0]);
        const float a1 = __builtin_amdgcn_exp2f(stA[4 * q + 1]);
        const float a2 = __builtin_amdgcn_exp2f(stA[4 * q + 2]);
        const float a3 = __builtin_amdgcn_exp2f(stA[4 * q + 3]);
        pkA[q][0] = cvtpk_bf16(a0, a1);
        pkA[q][1] = cvtpk_bf16(a2, a3);
        llA += (a0 + a1) + (a2 + a3);
        const float b0 = __builtin_amdgcn_exp2f(stB[4 * q + 0]);
        const float b1 = __builtin_amdgcn_exp2f(stB[4 * q + 1]);
        const float b2 = __builtin_amdgcn_exp2f(stB[4 * q + 2]);
        const float b3 = __builtin_amdgcn_exp2f(stB[4 * q + 3]);
        pkB[q][0] = cvtpk_bf16(b0, b1);
        pkB[q][1] = cvtpk_bf16(b2, b3);
        llB += (b0 + b1) + (b2 + b3);
      }
      // GEMM2: V fragment read once, used by both groups.
      __builtin_amdgcn_s_setprio(1);
#pragma unroll
      for (int m = 0; m < 2; ++m) {
        const int mi = pg * 2 + m;
        u32x4 faA, faB;
        faA[0] = pkA[2 * m][0];
        faA[1] = pkA[2 * m][1];
        faA[2] = pkA[2 * m + 1][0];
        faA[3] = pkA[2 * m + 1][1];
        faB[0] = pkB[2 * m][0];
        faB[1] = pkB[2 * m][1];
        faB[2] = pkB[2 * m + 1][0];
        faB[3] = pkB[2 * m + 1][1];
        const s16x8 pafA = __builtin_bit_cast(s16x8, faA);
        const s16x8 pafB = __builtin_bit_cast(s16x8, faB);
#pragma unroll
        for (int nd = 0; nd < 2; ++nd) {
          const uint2 vlo = *(const uint2*)&vt_lds[buf][voffs[nd][mi][0]];
          const uint2 vhi = *(const uint2*)&vt_lds[buf][voffs[nd][mi][1]];
          u32x4 vbu;
          vbu[0] = vlo.x;
          vbu[1] = vlo.y;
          vbu[2] = vhi.x;
          vbu[3] = vhi.y;
          const s16x8 vb = __builtin_bit_cast(s16x8, vbu);
          oaccA[nd] = mfma32(pafA, vb, oaccA[nd]);
          oaccB[nd] = mfma32(pafB, vb, oaccB[nd]);
        }
      }
      __builtin_amdgcn_s_setprio(0);
    }
  }

  // l per qrow (each group): lane (lc,hi) holds partial over half the pos
  // set; partner (lc,hi^1) the rest. Gather per output row via shfl.
  const float lqA = llA + __shfl_xor(llA, 32, 64);
  const float lqB = llB + __shfl_xor(llB, 32, 64);
  float linvA[16], linvB[16];
#pragma unroll
  for (int r = 0; r < 16; ++r) {
    const int qr = (r & 3) + 8 * (r >> 2) + 4 * hi;
    linvA[r] = 1.0f / __shfl(lqA, qr, 64);
    linvB[r] = 1.0f / __shfl(lqB, qr, 64);
  }

  const int orow0 = qpair * 256 + w * 32;
#pragma unroll
  for (int nd = 0; nd < 2; ++nd)
#pragma unroll
    for (int r = 0; r < 16; ++r) {
      const int qr = (r & 3) + 8 * (r >> 2) + 4 * hi;
      const int d = nd * 32 + lc;
      og[(size_t)(b * 1024 + orow0 + qr) * 768 + h * 64 + d] =
          f2bf(oaccA[nd][r] * linvA[r]);
      og[(size_t)(b * 1024 + orow0 + 128 + qr) * 768 + h * 64 + d] =
          f2bf(oaccB[nd][r] * linvB[r]);
    }
}

// ---------------- proj GEMM: [16384,768] x [768,768]^T + b_eff -> f32 out ----
// Operand-swapped: reg r -> out col n, packed float4 stores. Dbuf staging.

__global__ __launch_bounds__(256) void k_gemm_proj(
    const unsigned short* __restrict__ A, const unsigned short* __restrict__ Bw,
    const float* __restrict__ bias, float* __restrict__ out) {
  __shared__ short la[2][128 * 32];
  __shared__ short lb[2][128 * 32];
  const int t = threadIdx.x;
  const int w = t >> 6, l = t & 63;
  const int i = l & 15, qd = l >> 4;
  const int wm = w >> 1, wn = w & 1;
  const int mblk = blockIdx.x, nblk = blockIdx.y;

  const unsigned short* Ab = A + (size_t)(mblk * 128) * 768;
  const unsigned short* Bb = Bw + (size_t)(nblk * 128) * 768;
  const int sr = l >> 2;
  const int sc = (l & 3) * 8;

  auto stage = [&](int bufn, int kb_) {
    const int k0 = kb_ * 32;
#pragma unroll
    for (int j = 0; j < 2; ++j) {
      const int row = w * 32 + j * 16 + sr;
      async16(Ab + row * 768 + k0 + sc, &la[bufn][(w * 32 + j * 16) * 32]);
      async16(Bb + row * 768 + k0 + sc, &lb[bufn][(w * 32 + j * 16) * 32]);
    }
  };

  stage(0, 0);

  f32x4 acc[4][4] = {};

  for (int kb_ = 0; kb_ < 24; ++kb_) {
    const int buf = kb_ & 1;
    __syncthreads();
    if (kb_ < 23) stage(buf ^ 1, kb_ + 1);
    s16x8 af[4], bf[4];
#pragma unroll
    for (int mi = 0; mi < 4; ++mi)
      af[mi] = *(const s16x8*)&la[buf][(wm * 64 + mi * 16 + i) * 32 + qd * 8];
#pragma unroll
    for (int ni = 0; ni < 4; ++ni)
      bf[ni] = *(const s16x8*)&lb[buf][(wn * 64 + ni * 16 + i) * 32 + qd * 8];
#pragma unroll
    for (int mi = 0; mi < 4; ++mi)
#pragma unroll
      for (int ni = 0; ni < 4; ++ni)
        acc[mi][ni] = mfma16(bf[ni], af[mi], acc[mi][ni]);  // swapped
  }

#pragma unroll
  for (int ni = 0; ni < 4; ++ni) {
    const int n0 = nblk * 128 + wn * 64 + ni * 16 + qd * 4;
    const float4 bv4 = *(const float4*)(bias + n0);
#pragma unroll
    for (int mi = 0; mi < 4; ++mi) {
      const int m = mblk * 128 + wm * 64 + mi * 16 + i;
      float4 o;
      o.x = acc[mi][ni][0] + bv4.x;
      o.y = acc[mi][ni][1] + bv4.y;
      o.z = acc[mi][ni][2] + bv4.z;
      o.w = acc[mi][ni][3] + bv4.w;
      *(float4*)&out[(size_t)m * 768 + n0] = o;
    }
  }
}

// ---------------- host ----------------

extern "C" void kernel_launch(void* const* d_in, const int* in_sizes, int n_in,
                              void* d_out, int out_size, void* d_ws, size_t ws_size,
                              hipStream_t stream) {
  const float* x = (const float*)d_in[0];
  const float* Wqkv = (const float*)d_in[1];
  const float* bqkv = (const float*)d_in[2];
  const float* Wp = (const float*)d_in[3];
  const float* bp = (const float*)d_in[4];
  const float* Aq = (const float*)d_in[5];
  const float* Bq = (const float*)d_in[6];
  const float* Ak = (const float*)d_in[7];
  const float* Bk = (const float*)d_in[8];
  const float* Av = (const float*)d_in[9];
  const float* Bv = (const float*)d_in[10];
  const float* Ao = (const float*)d_in[11];
  const float* Bo = (const float*)d_in[12];
  float* out = (float*)d_out;

  unsigned short* xb = (unsigned short*)d_ws;         // 16384*768
  unsigned short* wqkvb = xb + (size_t)MTOT * C;      // 2304*768
  unsigned short* wpeb = wqkvb + (size_t)N3 * C;      // 768*768
  unsigned short* qb = wpeb + (size_t)C * C;          // 192*1024*64
  unsigned short* kb = qb + (size_t)MTOT * C;
  unsigned short* vtb = kb + (size_t)MTOT * C;        // 192*64*1024 (transposed)
  float* Mbuf = (float*)(vtb + (size_t)MTOT * C);     // 16*768
  float* beff = Mbuf + 16 * 768;                      // 768
  unsigned short* ob = xb;  // alias: xb dead after QKV gemm

  k_prep_all<<<19393, 256, 0, stream>>>(x, xb, Wqkv, Aq, Bq, Ak, Bk, Av, Bv,
                                        wqkvb, Ao, Wp, Mbuf, bp, Bo, beff);
  k_prep_wpe<<<2304, 256, 0, stream>>>(Wp, Bo, Mbuf, wpeb);

  k_gemm_qkv<<<dim3(128, 18), 256, 0, stream>>>(xb, wqkvb, bqkv, qb, kb, vtb);
  k_attn<<<dim3(192, 4), 256, 0, stream>>>(qb, kb, vtb, ob);
  k_gemm_proj<<<dim3(128, 6), 256, 0, stream>>>(ob, wpeb, beff, out);
}